// Round 24
// baseline (175.044 us; speedup 1.0000x reference)
//
#include <hip/hip_runtime.h>
#include <math.h>

#define TT 8
#define NNODES 20000
#define NEDGES 320000
#define FDIM 128
#define HDIM 128
#define BGR 64
#define NCLS 16
#define NBD 157   // dst buckets of 128 nodes (157*128 = 20096)
#define NBS 313   // src buckets of 64 nodes  (313*64  = 20032)
#define CB 80     // edge chunks per timestep
#define EC 4000   // edges per chunk (80*4000 = 320000)
#define CAPD 2816 // dst bucket capacity (mean 2038)
#define CAPS 1536 // src bucket capacity (mean 1022)

typedef short short8 __attribute__((ext_vector_type(8)));
typedef float f32x4 __attribute__((ext_vector_type(4)));

__device__ __forceinline__ float lrelu(float x) { return fmaxf(x, 0.2f * x); }
__device__ __forceinline__ float sigmoidf(float x) { return 1.0f / (1.0f + __expf(-x)); }
__device__ __forceinline__ float tanh_fast(float x) {
  return 1.0f - 2.0f / (__expf(2.0f * x) + 1.0f);
}
__device__ __forceinline__ unsigned short f2bf(float f) {   // RNE
  unsigned int u = __float_as_uint(f);
  unsigned int r = (u + 0x7fff + ((u >> 16) & 1)) >> 16;
  return (unsigned short)r;
}
__device__ __forceinline__ float bf_lo(unsigned int u) { return __uint_as_float(u << 16); }
__device__ __forceinline__ float bf_hi(unsigned int u) { return __uint_as_float(u & 0xffff0000u); }

// ---------------- prep: u = W@att_src, v = W@att_dst (one block, one-time)
__global__ __launch_bounds__(256) void k_prep(
    const float* __restrict__ W, const float* __restrict__ att_s, const float* __restrict__ att_d,
    float* __restrict__ u, float* __restrict__ v) {
  const int tid = threadIdx.x;
  if (tid < 128) {
    float su = 0.f, sv = 0.f;
    const float4* wr = (const float4*)(W + (size_t)tid * 128);
    #pragma unroll 8
    for (int q = 0; q < 32; ++q) {
      float4 w4 = wr[q];
      float4 a4 = *(const float4*)(att_s + q * 4);
      float4 d4 = *(const float4*)(att_d + q * 4);
      su += w4.x * a4.x + w4.y * a4.y + w4.z * a4.z + w4.w * a4.w;
      sv += w4.x * d4.x + w4.y * d4.y + w4.z * d4.z + w4.w * d4.w;
    }
    u[tid] = su; v[tid] = sv;
  }
}

// ---------------- GEMV: as = x@u, ad = x@v; denom seed fused; ALSO emits
// xb = pair-packed bf16 copy of x (uint slot j = (x[j], x[j+64])). No LDS.
__global__ __launch_bounds__(256) void k_gemv(
    const float* __restrict__ x, const float* __restrict__ u, const float* __restrict__ v,
    float* __restrict__ as_, float* __restrict__ ad_, float* __restrict__ denom,
    unsigned int* __restrict__ xb) {
  const int tid = threadIdx.x;
  const int c4 = tid & 31;
  const int ty = tid >> 5;           // 0..7: row within iteration
  const int lane = tid & 63;
  float4 uu = *(const float4*)(u + c4 * 4);
  float4 vv = *(const float4*)(v + c4 * 4);
  const int base = blockIdx.x * 64;
  #pragma unroll
  for (int it = 0; it < 8; ++it) {
    int r = base + it * 8 + ty;
    float4 xv = *(const float4*)(x + (size_t)r * FDIM + c4 * 4);
    float ps = xv.x * uu.x + xv.y * uu.y + xv.z * uu.z + xv.w * uu.w;
    float pd = xv.x * vv.x + xv.y * vv.y + xv.z * vv.z + xv.w * vv.w;
    float4 px;   // partner lane (c4+16) holds floats 64+c4*4.. of same row
    px.x = __shfl_xor(xv.x, 16);
    px.y = __shfl_xor(xv.y, 16);
    px.z = __shfl_xor(xv.z, 16);
    px.w = __shfl_xor(xv.w, 16);
    if (c4 < 16) {
      uint4 pk;
      pk.x = (unsigned int)f2bf(xv.x) | ((unsigned int)f2bf(px.x) << 16);
      pk.y = (unsigned int)f2bf(xv.y) | ((unsigned int)f2bf(px.y) << 16);
      pk.z = (unsigned int)f2bf(xv.z) | ((unsigned int)f2bf(px.z) << 16);
      pk.w = (unsigned int)f2bf(xv.w) | ((unsigned int)f2bf(px.w) << 16);
      *(uint4*)(xb + (size_t)r * 64 + c4 * 4) = pk;
    }
    #pragma unroll
    for (int o = 16; o > 0; o >>= 1) { ps += __shfl_xor(ps, o); pd += __shfl_xor(pd, o); }
    if ((lane & 31) == 0) {
      as_[r] = ps;
      ad_[r] = pd;
      denom[r] = __expf(lrelu(ps + pd));   // self-loop seeds denominator
    }
  }
}

// ---------------- partition: single ei read, LDS record buffer, global base
// reservation, scatter from LDS. DUAL granularity: dst->128-node (NBD),
// src->64-node (NBS).
__global__ __launch_bounds__(256) void k_scat(
    const int* __restrict__ ei, int* __restrict__ cnt_d, int* __restrict__ cnt_s,
    unsigned int* __restrict__ part_d, unsigned int* __restrict__ part_s) {
  __shared__ unsigned int buf[EC];  // 16 KB record buffer
  __shared__ int hd[NBD], hs[NBS];  // histogram, then cursors
  __shared__ int bd[NBD], bs[NBS];  // reserved base offsets
  const int tid = threadIdx.x;
  const int chunk = blockIdx.x, t = blockIdx.y;
  for (int i = tid; i < NBS; i += 256) { hs[i] = 0; if (i < NBD) hd[i] = 0; }
  __syncthreads();
  const int* eis = ei + (size_t)t * 2 * NEDGES;
  for (int i = tid; i < EC; i += 256) {   // pass 1: read once, buffer + histogram
    int e = chunk * EC + i;
    int s = eis[e], d = eis[NEDGES + e];
    buf[i] = ((unsigned int)s << 15) | (unsigned int)d;
    atomicAdd(&hd[d >> 7], 1);
    atomicAdd(&hs[s >> 6], 1);
  }
  __syncthreads();
  for (int i = tid; i < NBS; i += 256) {    // reserve global bases; reset cursors
    bs[i] = atomicAdd(&cnt_s[t * NBS + i], hs[i]);
    hs[i] = 0;
    if (i < NBD) {
      bd[i] = atomicAdd(&cnt_d[t * NBD + i], hd[i]);
      hd[i] = 0;
    }
  }
  __syncthreads();
  unsigned int* pdt = part_d + (size_t)t * NBD * CAPD;
  unsigned int* pst = part_s + (size_t)t * NBS * CAPS;
  for (int i = tid; i < EC; i += 256) {   // pass 2: scatter from LDS
    unsigned int rec = buf[i];
    int d = rec & 32767, s = rec >> 15;
    int Bd = d >> 7, Bs = s >> 6;
    int od = bd[Bd] + atomicAdd(&hd[Bd], 1);
    pdt[Bd * CAPD + od] = rec;
    int os = bs[Bs] + atomicAdd(&hs[Bs], 1);
    pst[Bs * CAPS + os] = rec;
  }
}

// ---------------- denominator from dst-partition (128-node buckets);
// aux4=(ad, 1/denom, batch-bits, 0) fused; k_starts folded (t==0 slices).
__global__ __launch_bounds__(256) void k_denomB(
    const unsigned int* __restrict__ part_d, const int* __restrict__ cnt_d,
    const float* __restrict__ as_, const float* __restrict__ ad_,
    const float* __restrict__ dseed, const int* __restrict__ batch,
    float4* __restrict__ aux4, int* __restrict__ starts) {
  __shared__ float hist[128];
  __shared__ float adl[128];
  const int tid = threadIdx.x;
  const int B = blockIdx.x, t = blockIdx.y;
  if (tid < 128) {
    hist[tid] = 0.f;
    int n = B * 128 + tid;
    adl[tid] = (n < NNODES) ? ad_[t * NNODES + n] : 0.f;
  }
  __syncthreads();
  const int cnt = cnt_d[t * NBD + B];
  const unsigned int* pdt = part_d + ((size_t)t * NBD + B) * CAPD;
  const float* asb = as_ + (size_t)t * NNODES;
  int i = tid;
  for (; i + 768 < cnt; i += 1024) {   // 4 independent gather chains
    unsigned int r0 = pdt[i], r1 = pdt[i + 256], r2 = pdt[i + 512], r3 = pdt[i + 768];
    float v0 = asb[r0 >> 15], v1 = asb[r1 >> 15], v2 = asb[r2 >> 15], v3 = asb[r3 >> 15];
    float w0 = __expf(lrelu(v0 + adl[r0 & 127]));
    float w1 = __expf(lrelu(v1 + adl[r1 & 127]));
    float w2 = __expf(lrelu(v2 + adl[r2 & 127]));
    float w3 = __expf(lrelu(v3 + adl[r3 & 127]));
    atomicAdd(&hist[r0 & 127], w0);
    atomicAdd(&hist[r1 & 127], w1);
    atomicAdd(&hist[r2 & 127], w2);
    atomicAdd(&hist[r3 & 127], w3);
  }
  for (; i < cnt; i += 256) {
    unsigned int rec = pdt[i];
    float w = __expf(lrelu(asb[rec >> 15] + adl[rec & 127]));
    atomicAdd(&hist[rec & 127], w);
  }
  __syncthreads();
  if (tid < 128) {
    int n = B * 128 + tid;
    if (n < NNODES) {
      float den = dseed[t * NNODES + n] + hist[tid];
      int bn = batch[n];
      aux4[t * NNODES + n] = make_float4(adl[tid], 1.0f / den, __int_as_float(bn), 0.f);
      if (t == 0) {   // folded k_starts (batch is sorted)
        if (n == 0) { for (int bb = 0; bb <= bn; ++bb) starts[bb] = 0; }
        else { int pb = batch[n - 1]; for (int bb = pb + 1; bb <= bn; ++bb) starts[bb] = n; }
        if (n == NNODES - 1) { for (int bb = bn + 1; bb <= BGR; ++bb) starts[bb] = NNODES; }
      }
    }
  }
}

// ---------------- FUSED c-build + P-partial per (src-bucket B, t in {y, y+4}).
// TWO timesteps per block: grid 313x4 = 1252 blocks ~ 4.9/CU < 5 resident
// (27.6 KB LDS) -> single co-resident dispatch wave, no tail quantization.
// Phase 1: edge pass -> clT fp32 [k][b] via LDS atomics.
// Phase 2 (MFMA): clA bf16 [b][k] + xT bf16 [d][k] (stride 72), xT aliased
// over clT. D = clA @ xT^T via mfma_f32_16x16x32_bf16 (same k-slot map for
// A and B; C/D: col=lane&15, row=(lane>>4)*4+reg [m89]).
__global__ __launch_bounds__(256) void k_cpgemm(
    const unsigned int* __restrict__ part_s, const int* __restrict__ cnt_s,
    const float* __restrict__ as_, const float4* __restrict__ aux4,
    const unsigned int* __restrict__ xb, unsigned int* __restrict__ ppart) {
  __shared__ char lds0[128 * 72 * 2];          // 18432 B: clT fp32 [64][64] then xT bf16 [128][72]
  __shared__ unsigned short clA[64 * 72];      // 9216 B: A operand bf16 [b][k]
  float* clT = (float*)lds0;
  unsigned short* xT = (unsigned short*)lds0;
  const int tid = threadIdx.x;
  const int lane = tid & 63;
  const int w = tid >> 6;
  const int B = blockIdx.x;
  #pragma unroll
  for (int tt = 0; tt < 2; ++tt) {
    const int t = blockIdx.y + tt * 4;
    __syncthreads();   // protect lds0 (xT of previous iter) before re-zeroing
    #pragma unroll
    for (int i = tid; i < 64 * 64; i += 256) clT[i] = 0.f;
    const float* asb = as_ + (size_t)t * NNODES;
    float a0 = asb[min(B * 64 + lane, NNODES - 1)];   // asl[lane]
    __syncthreads();
    const float4* auxt = aux4 + (size_t)t * NNODES;
    if (tid < 64) {   // self-loop coefficient (atomic: no ordering hazard)
      int n = B * 64 + tid;
      if (n < NNODES) {
        float4 aa = auxt[n];
        float wself = __expf(lrelu(asb[n] + aa.x)) * aa.y;
        atomicAdd(&clT[tid * 64 + __float_as_int(aa.z)], wself);
      }
    }
    {
      const int cnt = cnt_s[t * NBS + B];
      const unsigned int* pst = part_s + ((size_t)t * NBS + B) * CAPS;
      int i = tid;
      for (; i + 768 < cnt; i += 1024) {   // 4 independent chains in flight
        unsigned int r0 = pst[i], r1 = pst[i + 256], r2 = pst[i + 512], r3 = pst[i + 768];
        float4 x0 = auxt[r0 & 32767], x1 = auxt[r1 & 32767];
        float4 x2 = auxt[r2 & 32767], x3 = auxt[r3 & 32767];
        int s0 = (int)(r0 >> 15) & 63, s1 = (int)(r1 >> 15) & 63;
        int s2 = (int)(r2 >> 15) & 63, s3 = (int)(r3 >> 15) & 63;
        float v0 = __shfl(a0, s0), v1 = __shfl(a0, s1);
        float v2 = __shfl(a0, s2), v3 = __shfl(a0, s3);
        float w0 = __expf(lrelu(v0 + x0.x)) * x0.y;
        float w1 = __expf(lrelu(v1 + x1.x)) * x1.y;
        float w2 = __expf(lrelu(v2 + x2.x)) * x2.y;
        float w3 = __expf(lrelu(v3 + x3.x)) * x3.y;
        atomicAdd(&clT[s0 * 64 + __float_as_int(x0.z)], w0);
        atomicAdd(&clT[s1 * 64 + __float_as_int(x1.z)], w1);
        atomicAdd(&clT[s2 * 64 + __float_as_int(x2.z)], w2);
        atomicAdd(&clT[s3 * 64 + __float_as_int(x3.z)], w3);
      }
      for (; i < cnt; i += 256) {
        unsigned int rec = pst[i];
        int s6 = (int)(rec >> 15) & 63;
        float4 aa = auxt[rec & 32767];
        float v = __shfl(a0, s6);
        float w2 = __expf(lrelu(v + aa.x)) * aa.y;
        atomicAdd(&clT[s6 * 64 + __float_as_int(aa.z)], w2);
      }
    }
    __syncthreads();
    // build clA bf16 [b][k] (stride 72 shorts = 36 uints) from clT [k][b]
    {
      unsigned int* clAu = (unsigned int*)clA;
      const int b = tid & 63, seg = tid >> 6;   // seg 0..3
      #pragma unroll
      for (int q = 0; q < 8; ++q) {
        int up = seg * 8 + q;                   // uint index 0..31 (k pair)
        int k = up * 2;
        unsigned int pk = (unsigned int)f2bf(clT[k * 64 + b]) |
                          ((unsigned int)f2bf(clT[(k + 1) * 64 + b]) << 16);
        clAu[b * 36 + up] = pk;
      }
    }
    __syncthreads();   // clT reads complete; safe to overwrite region with xT
    // build xT bf16 [d][k] (stride 72 shorts) from pair-packed xb rows
    {
      const unsigned int* xrow = xb + (size_t)t * NNODES * 64;
      unsigned int* xTu = (unsigned int*)xT;
      const int j = tid & 63, kp = tid >> 6;    // kp 0..3
      #pragma unroll
      for (int p = 0; p < 8; ++p) {
        int kk = (kp * 8 + p) * 2;
        int r0 = B * 64 + kk;     r0 = (r0 < NNODES) ? r0 : (NNODES - 1);
        int r1 = B * 64 + kk + 1; r1 = (r1 < NNODES) ? r1 : (NNODES - 1);
        unsigned int ua = xrow[(size_t)r0 * 64 + j];   // (x[kk][j], x[kk][j+64])
        unsigned int ub = xrow[(size_t)r1 * 64 + j];
        xTu[j * 36 + (kk >> 1)]        = (ua & 0xffffu) | (ub << 16);
        xTu[(j + 64) * 36 + (kk >> 1)] = (ua >> 16) | (ub & 0xffff0000u);
      }
    }
    __syncthreads();
    // MFMA: wave w owns b-stripe bs = w*16; D[b][d] over d = 0..127
    const int ln = lane & 15, hi = lane >> 4;
    const int bs = w * 16;
    f32x4 acc[8] = {};
    #pragma unroll
    for (int kh = 0; kh < 2; ++kh) {
      short8 a = *(const short8*)&clA[(bs + ln) * 72 + kh * 32 + hi * 8];
      #pragma unroll
      for (int ni = 0; ni < 8; ++ni) {
        short8 bfr = *(const short8*)&xT[(ni * 16 + ln) * 72 + kh * 32 + hi * 8];
        acc[ni] = __builtin_amdgcn_mfma_f32_16x16x32_bf16(a, bfr, acc[ni], 0, 0, 0);
      }
    }
    unsigned int* pp = ppart + ((size_t)t * NBS + B) * BGR * 64;
    #pragma unroll
    for (int ni = 0; ni < 4; ++ni)
      #pragma unroll
      for (int r = 0; r < 4; ++r) {   // pair-pack (d, d+64) = (acc[ni], acc[ni+4])
        unsigned int pk = (unsigned int)f2bf(acc[ni][r]) |
                          ((unsigned int)f2bf(acc[ni + 4][r]) << 16);
        pp[(bs + hi * 4 + r) * 64 + ni * 16 + ln] = pk;
      }
  }
}

// ---------------- pooled = (sum_B P) @ W * invc + gat_bias  (block per (t,b))
// 128 threads: tid<64 sums buckets [0,157), tid>=64 sums [157,313); LDS combine.
__global__ __launch_bounds__(128) void k_pw(
    const unsigned int* __restrict__ ppart, const int* __restrict__ starts,
    const float* __restrict__ W, const float* __restrict__ gat_bias,
    float* __restrict__ pooled) {
  __shared__ float srow[128];
  __shared__ float psum[2][128];
  const int tb = blockIdx.x;       // 0..511
  const int t = tb >> 6, b = tb & 63;
  const int d = threadIdx.x & 63, half = threadIdx.x >> 6;
  {
    float slo = 0.f, shi = 0.f;
    const int B0 = half ? 157 : 0, B1 = half ? NBS : 157;
    const unsigned int* pp = ppart + ((size_t)t * NBS * BGR + b) * 64 + d;
    #pragma unroll 4
    for (int B = B0; B < B1; ++B) {
      unsigned int u = pp[(size_t)B * BGR * 64];
      slo += bf_lo(u); shi += bf_hi(u);
    }
    psum[half][d] = slo; psum[half][64 + d] = shi;
  }
  __syncthreads();
  if (threadIdx.x < 128) srow[threadIdx.x] = psum[0][threadIdx.x] + psum[1][threadIdx.x];
  __syncthreads();
  const float invc = 1.0f / (float)max(starts[b + 1] - starts[b], 1);
  const int dd = threadIdx.x;
  float o = 0.f;
  #pragma unroll 8
  for (int k = 0; k < 128; ++k) o += srow[k] * W[k * 128 + dd];
  pooled[(size_t)(t * BGR + b) * HDIM + dd] = o * invc + gat_bias[dd];
}

// ---------------- LSTM over T + fused FC (one block per batch row b)
__global__ __launch_bounds__(512) void k_lstm_fc(
    const float* __restrict__ pooled,
    const float* __restrict__ W_ih, const float* __restrict__ W_hh,
    const float* __restrict__ b_ih, const float* __restrict__ b_hh,
    const float* __restrict__ z, const float* __restrict__ fc_W,
    const float* __restrict__ fc_b, float* __restrict__ out) {
  const int b = blockIdx.x;
  const int g = threadIdx.x;
  __shared__ unsigned int wpk[512 * 65];
  __shared__ float hv[128], cv[128], part[512];
  __shared__ float pool8[TT][128];
  __shared__ float fcp[16][17];

  #pragma unroll 2
  for (int it = 0; it < 64; ++it) {
    int i = g + it * 512;
    int gr = i >> 6, j = i & 63;
    float2 wv = *(const float2*)(W_hh + (size_t)gr * HDIM + j * 2);
    wpk[gr * 65 + j] = (unsigned int)f2bf(wv.x) | ((unsigned int)f2bf(wv.y) << 16);
  }
  #pragma unroll
  for (int i = 0; i < 2; ++i) {
    int idx = g + i * 512;
    int t = idx >> 7, k = idx & 127;
    pool8[t][k] = pooled[((size_t)t * BGR + b) * HDIM + k];
  }
  if (g < 128) { hv[g] = 0.f; cv[g] = 0.f; }
  __syncthreads();

  float gx[8] = {};
  {
    const float4* wi = (const float4*)(W_ih + (size_t)g * HDIM);
    #pragma unroll 2
    for (int k4 = 0; k4 < 32; ++k4) {
      float4 wv = wi[k4];
      #pragma unroll
      for (int t = 0; t < TT; ++t) {
        float4 p = *(const float4*)(&pool8[t][k4 * 4]);
        gx[t] += wv.x * p.x + wv.y * p.y + wv.z * p.z + wv.w * p.w;
      }
    }
  }
  const float bsum = b_ih[g] + b_hh[g];
  const unsigned int* wr = &wpk[g * 65];
  const float4* hv4 = (const float4*)hv;
  #pragma unroll
  for (int t = 0; t < TT; ++t) {
    float s = gx[t] + bsum;
    #pragma unroll 8
    for (int j2 = 0; j2 < 32; ++j2) {
      unsigned int w0 = wr[2 * j2], w1 = wr[2 * j2 + 1];
      float4 hh = hv4[j2];
      s += bf_lo(w0) * hh.x + bf_hi(w0) * hh.y + bf_lo(w1) * hh.z + bf_hi(w1) * hh.w;
    }
    part[g] = s;
    __syncthreads();
    if (g < 128) {
      float ig = sigmoidf(part[g]);
      float fg = sigmoidf(part[128 + g]);
      float gc = tanh_fast(part[256 + g]);
      float og = sigmoidf(part[384 + g]);
      float c = fg * cv[g] + ig * gc;
      cv[g] = c;
      hv[g] = og * tanh_fast(c);
    }
    __syncthreads();
  }
  if (g < 256) {
    const int c = g >> 4, kp = g & 15;
    float s = 0.f;
    for (int k = kp * 16; k < kp * 16 + 16; ++k) {
      float v = (k < 128) ? hv[k] : z[(size_t)b * HDIM + (k - 128)];
      s += v * fc_W[(size_t)c * 256 + k];
    }
    fcp[c][kp] = s;
  }
  __syncthreads();
  if (g < 16) {
    float r = fc_b[g];
    #pragma unroll
    for (int k = 0; k < 16; ++k) r += fcp[g][k];
    out[(size_t)b * NCLS + g] = r;
  }
}

extern "C" void kernel_launch(void* const* d_in, const int* in_sizes, int n_in,
                              void* d_out, int out_size, void* d_ws, size_t ws_size,
                              hipStream_t stream) {
  const float* x       = (const float*)d_in[0];
  const int*   ei      = (const int*)d_in[1];
  const int*   batch   = (const int*)d_in[2];
  const float* z       = (const float*)d_in[3];
  const float* gat_W   = (const float*)d_in[4];
  const float* att_src = (const float*)d_in[5];
  const float* att_dst = (const float*)d_in[6];
  const float* gat_bias= (const float*)d_in[7];
  const float* W_ih    = (const float*)d_in[8];
  const float* W_hh    = (const float*)d_in[9];
  const float* b_ih    = (const float*)d_in[10];
  const float* b_hh    = (const float*)d_in[11];
  const float* fc_W    = (const float*)d_in[12];
  const float* fc_b    = (const float*)d_in[13];
  float* out = (float*)d_out;

  char* ws = (char*)d_ws;
  size_t off = 0;
  auto alloc = [&](size_t bytes) {
    void* p = (void*)(ws + off);
    off += (bytes + 255) & ~(size_t)255;
    return p;
  };
  float*  as_    = (float*)alloc((size_t)TT * NNODES * 4);
  float*  ad_    = (float*)alloc((size_t)TT * NNODES * 4);
  float*  denom  = (float*)alloc((size_t)TT * NNODES * 4);
  float4* aux4   = (float4*)alloc((size_t)TT * NNODES * 16);                      // 2.56 MB
  int*    cnt2   = (int*)alloc((size_t)TT * (NBD + NBS) * 4);       // cnt_d | cnt_s (one memset)
  int*    cnt_d  = cnt2;
  int*    cnt_s  = cnt2 + TT * NBD;
  unsigned int* part_d = (unsigned int*)alloc(((size_t)TT * NBD + 1) * CAPD * 4); // 14.2 MB (+slack)
  unsigned int* part_s = (unsigned int*)alloc(((size_t)TT * NBS + 1) * CAPS * 4); // 15.4 MB (+slack)
  unsigned int* ppart  = (unsigned int*)alloc((size_t)TT * NBS * BGR * 64 * 4);   // 41.0 MB bf16-packed
  unsigned int* xb     = (unsigned int*)alloc((size_t)TT * NNODES * 64 * 4);      // 40.96 MB bf16-packed
  float* uvec  = (float*)alloc(128 * 4);
  float* vvec  = (float*)alloc(128 * 4);
  float* pooled = (float*)alloc((size_t)TT * BGR * HDIM * 4);
  int* starts = (int*)alloc((BGR + 1) * 4);
  (void)ws_size; (void)in_sizes; (void)n_in; (void)out_size;

  hipMemsetAsync(cnt2, 0, (size_t)TT * (NBD + NBS) * 4, stream);

  k_prep<<<1, 256, 0, stream>>>(gat_W, att_src, att_dst, uvec, vvec);
  k_gemv<<<(TT * NNODES) / 64, 256, 0, stream>>>(x, uvec, vvec, as_, ad_, denom, xb);
  k_scat<<<dim3(CB, TT), 256, 0, stream>>>(ei, cnt_d, cnt_s, part_d, part_s);
  k_denomB<<<dim3(NBD, TT), 256, 0, stream>>>(part_d, cnt_d, as_, ad_, denom, batch, aux4, starts);
  k_cpgemm<<<dim3(NBS, 4), 256, 0, stream>>>(part_s, cnt_s, as_, aux4, xb, ppart);
  k_pw<<<TT * BGR, 128, 0, stream>>>(ppart, starts, gat_W, gat_bias, pooled);
  k_lstm_fc<<<BGR, 512, 0, stream>>>(pooled, W_ih, W_hh, b_ih, b_hh, z, fc_W, fc_b, out);
}

// Round 25
// 166.292 us; speedup vs baseline: 1.0526x; 1.0526x over previous
//
#include <hip/hip_runtime.h>
#include <math.h>

#define TT 8
#define NNODES 20000
#define NEDGES 320000
#define FDIM 128
#define HDIM 128
#define BGR 64
#define NCLS 16
#define NBD 157   // dst buckets of 128 nodes (157*128 = 20096)
#define NBS 313   // src buckets of 64 nodes  (313*64  = 20032)
#define CB 80     // edge chunks per timestep
#define EC 4000   // edges per chunk (80*4000 = 320000)
#define CAPD 2816 // dst bucket capacity (mean 2038)
#define CAPS 1536 // src bucket capacity (mean 1022)

typedef short short8 __attribute__((ext_vector_type(8)));
typedef float f32x4 __attribute__((ext_vector_type(4)));

__device__ __forceinline__ float lrelu(float x) { return fmaxf(x, 0.2f * x); }
__device__ __forceinline__ float sigmoidf(float x) { return 1.0f / (1.0f + __expf(-x)); }
__device__ __forceinline__ float tanh_fast(float x) {
  return 1.0f - 2.0f / (__expf(2.0f * x) + 1.0f);
}
__device__ __forceinline__ unsigned short f2bf(float f) {   // RNE
  unsigned int u = __float_as_uint(f);
  unsigned int r = (u + 0x7fff + ((u >> 16) & 1)) >> 16;
  return (unsigned short)r;
}
__device__ __forceinline__ float bf_lo(unsigned int u) { return __uint_as_float(u << 16); }
__device__ __forceinline__ float bf_hi(unsigned int u) { return __uint_as_float(u & 0xffff0000u); }

// ---------------- prep: u = W@att_src, v = W@att_dst (one block, one-time)
__global__ __launch_bounds__(256) void k_prep(
    const float* __restrict__ W, const float* __restrict__ att_s, const float* __restrict__ att_d,
    float* __restrict__ u, float* __restrict__ v) {
  const int tid = threadIdx.x;
  if (tid < 128) {
    float su = 0.f, sv = 0.f;
    const float4* wr = (const float4*)(W + (size_t)tid * 128);
    #pragma unroll 8
    for (int q = 0; q < 32; ++q) {
      float4 w4 = wr[q];
      float4 a4 = *(const float4*)(att_s + q * 4);
      float4 d4 = *(const float4*)(att_d + q * 4);
      su += w4.x * a4.x + w4.y * a4.y + w4.z * a4.z + w4.w * a4.w;
      sv += w4.x * d4.x + w4.y * d4.y + w4.z * d4.z + w4.w * d4.w;
    }
    u[tid] = su; v[tid] = sv;
  }
}

// ---------------- GEMV: as = x@u, ad = x@v; denom seed fused; ALSO emits
// xb = pair-packed bf16 copy of x (uint slot j = (x[j], x[j+64])). No LDS.
__global__ __launch_bounds__(256) void k_gemv(
    const float* __restrict__ x, const float* __restrict__ u, const float* __restrict__ v,
    float* __restrict__ as_, float* __restrict__ ad_, float* __restrict__ denom,
    unsigned int* __restrict__ xb) {
  const int tid = threadIdx.x;
  const int c4 = tid & 31;
  const int ty = tid >> 5;           // 0..7: row within iteration
  const int lane = tid & 63;
  float4 uu = *(const float4*)(u + c4 * 4);
  float4 vv = *(const float4*)(v + c4 * 4);
  const int base = blockIdx.x * 64;
  #pragma unroll
  for (int it = 0; it < 8; ++it) {
    int r = base + it * 8 + ty;
    float4 xv = *(const float4*)(x + (size_t)r * FDIM + c4 * 4);
    float ps = xv.x * uu.x + xv.y * uu.y + xv.z * uu.z + xv.w * uu.w;
    float pd = xv.x * vv.x + xv.y * vv.y + xv.z * vv.z + xv.w * vv.w;
    float4 px;   // partner lane (c4+16) holds floats 64+c4*4.. of same row
    px.x = __shfl_xor(xv.x, 16);
    px.y = __shfl_xor(xv.y, 16);
    px.z = __shfl_xor(xv.z, 16);
    px.w = __shfl_xor(xv.w, 16);
    if (c4 < 16) {
      uint4 pk;
      pk.x = (unsigned int)f2bf(xv.x) | ((unsigned int)f2bf(px.x) << 16);
      pk.y = (unsigned int)f2bf(xv.y) | ((unsigned int)f2bf(px.y) << 16);
      pk.z = (unsigned int)f2bf(xv.z) | ((unsigned int)f2bf(px.z) << 16);
      pk.w = (unsigned int)f2bf(xv.w) | ((unsigned int)f2bf(px.w) << 16);
      *(uint4*)(xb + (size_t)r * 64 + c4 * 4) = pk;
    }
    #pragma unroll
    for (int o = 16; o > 0; o >>= 1) { ps += __shfl_xor(ps, o); pd += __shfl_xor(pd, o); }
    if ((lane & 31) == 0) {
      as_[r] = ps;
      ad_[r] = pd;
      denom[r] = __expf(lrelu(ps + pd));   // self-loop seeds denominator
    }
  }
}

// ---------------- partition: single ei read, LDS record buffer, global base
// reservation, scatter from LDS. DUAL granularity: dst->128-node (NBD),
// src->64-node (NBS).
__global__ __launch_bounds__(256) void k_scat(
    const int* __restrict__ ei, int* __restrict__ cnt_d, int* __restrict__ cnt_s,
    unsigned int* __restrict__ part_d, unsigned int* __restrict__ part_s) {
  __shared__ unsigned int buf[EC];  // 16 KB record buffer
  __shared__ int hd[NBD], hs[NBS];  // histogram, then cursors
  __shared__ int bd[NBD], bs[NBS];  // reserved base offsets
  const int tid = threadIdx.x;
  const int chunk = blockIdx.x, t = blockIdx.y;
  for (int i = tid; i < NBS; i += 256) { hs[i] = 0; if (i < NBD) hd[i] = 0; }
  __syncthreads();
  const int* eis = ei + (size_t)t * 2 * NEDGES;
  for (int i = tid; i < EC; i += 256) {   // pass 1: read once, buffer + histogram
    int e = chunk * EC + i;
    int s = eis[e], d = eis[NEDGES + e];
    buf[i] = ((unsigned int)s << 15) | (unsigned int)d;
    atomicAdd(&hd[d >> 7], 1);
    atomicAdd(&hs[s >> 6], 1);
  }
  __syncthreads();
  for (int i = tid; i < NBS; i += 256) {    // reserve global bases; reset cursors
    bs[i] = atomicAdd(&cnt_s[t * NBS + i], hs[i]);
    hs[i] = 0;
    if (i < NBD) {
      bd[i] = atomicAdd(&cnt_d[t * NBD + i], hd[i]);
      hd[i] = 0;
    }
  }
  __syncthreads();
  unsigned int* pdt = part_d + (size_t)t * NBD * CAPD;
  unsigned int* pst = part_s + (size_t)t * NBS * CAPS;
  for (int i = tid; i < EC; i += 256) {   // pass 2: scatter from LDS
    unsigned int rec = buf[i];
    int d = rec & 32767, s = rec >> 15;
    int Bd = d >> 7, Bs = s >> 6;
    int od = bd[Bd] + atomicAdd(&hd[Bd], 1);
    pdt[Bd * CAPD + od] = rec;
    int os = bs[Bs] + atomicAdd(&hs[Bs], 1);
    pst[Bs * CAPS + os] = rec;
  }
}

// ---------------- denominator from dst-partition (128-node buckets);
// aux4=(ad, 1/denom, batch-bits, 0) fused; k_starts folded (t==0 slices).
__global__ __launch_bounds__(256) void k_denomB(
    const unsigned int* __restrict__ part_d, const int* __restrict__ cnt_d,
    const float* __restrict__ as_, const float* __restrict__ ad_,
    const float* __restrict__ dseed, const int* __restrict__ batch,
    float4* __restrict__ aux4, int* __restrict__ starts) {
  __shared__ float hist[128];
  __shared__ float adl[128];
  const int tid = threadIdx.x;
  const int B = blockIdx.x, t = blockIdx.y;
  if (tid < 128) {
    hist[tid] = 0.f;
    int n = B * 128 + tid;
    adl[tid] = (n < NNODES) ? ad_[t * NNODES + n] : 0.f;
  }
  __syncthreads();
  const int cnt = cnt_d[t * NBD + B];
  const unsigned int* pdt = part_d + ((size_t)t * NBD + B) * CAPD;
  const float* asb = as_ + (size_t)t * NNODES;
  int i = tid;
  for (; i + 768 < cnt; i += 1024) {   // 4 independent gather chains
    unsigned int r0 = pdt[i], r1 = pdt[i + 256], r2 = pdt[i + 512], r3 = pdt[i + 768];
    float v0 = asb[r0 >> 15], v1 = asb[r1 >> 15], v2 = asb[r2 >> 15], v3 = asb[r3 >> 15];
    float w0 = __expf(lrelu(v0 + adl[r0 & 127]));
    float w1 = __expf(lrelu(v1 + adl[r1 & 127]));
    float w2 = __expf(lrelu(v2 + adl[r2 & 127]));
    float w3 = __expf(lrelu(v3 + adl[r3 & 127]));
    atomicAdd(&hist[r0 & 127], w0);
    atomicAdd(&hist[r1 & 127], w1);
    atomicAdd(&hist[r2 & 127], w2);
    atomicAdd(&hist[r3 & 127], w3);
  }
  for (; i < cnt; i += 256) {
    unsigned int rec = pdt[i];
    float w = __expf(lrelu(asb[rec >> 15] + adl[rec & 127]));
    atomicAdd(&hist[rec & 127], w);
  }
  __syncthreads();
  if (tid < 128) {
    int n = B * 128 + tid;
    if (n < NNODES) {
      float den = dseed[t * NNODES + n] + hist[tid];
      int bn = batch[n];
      aux4[t * NNODES + n] = make_float4(adl[tid], 1.0f / den, __int_as_float(bn), 0.f);
      if (t == 0) {   // folded k_starts (batch is sorted)
        if (n == 0) { for (int bb = 0; bb <= bn; ++bb) starts[bb] = 0; }
        else { int pb = batch[n - 1]; for (int bb = pb + 1; bb <= bn; ++bb) starts[bb] = n; }
        if (n == NNODES - 1) { for (int bb = bn + 1; bb <= BGR; ++bb) starts[bb] = NNODES; }
      }
    }
  }
}

// ---------------- FUSED c-build + P-partial per (t, src-bucket B of 64 nodes).
// Phase 1: edge pass -> clT fp32 [k][b] via LDS atomics.
// Phase 2 (MFMA): clA bf16 [b][k] + xT bf16 [d][k] (stride 72 shorts), xT
// aliased OVER clT. D = clA @ xT^T via mfma_f32_16x16x32_bf16: same k-slot
// map for A and B (contraction invariant), C/D: col=lane&15,
// row=(lane>>4)*4+reg [m89]. LDS 27.6 KB -> 5 blocks/CU.
__global__ __launch_bounds__(256) void k_cpgemm(
    const unsigned int* __restrict__ part_s, const int* __restrict__ cnt_s,
    const float* __restrict__ as_, const float4* __restrict__ aux4,
    const unsigned int* __restrict__ xb, unsigned int* __restrict__ ppart) {
  __shared__ char lds0[128 * 72 * 2];          // 18432 B: clT fp32 [64][64] then xT bf16 [128][72]
  __shared__ unsigned short clA[64 * 72];      // 9216 B: A operand bf16 [b][k]
  float* clT = (float*)lds0;
  unsigned short* xT = (unsigned short*)lds0;
  const int tid = threadIdx.x;
  const int lane = tid & 63;
  const int w = tid >> 6;
  const int B = blockIdx.x, t = blockIdx.y;
  #pragma unroll
  for (int i = tid; i < 64 * 64; i += 256) clT[i] = 0.f;
  const float* asb = as_ + (size_t)t * NNODES;
  float a0 = asb[min(B * 64 + lane, NNODES - 1)];   // asl[lane]
  __syncthreads();
  const float4* auxt = aux4 + (size_t)t * NNODES;
  if (tid < 64) {   // self-loop coefficient (atomic: no ordering hazard)
    int n = B * 64 + tid;
    if (n < NNODES) {
      float4 aa = auxt[n];
      float wself = __expf(lrelu(asb[n] + aa.x)) * aa.y;
      atomicAdd(&clT[tid * 64 + __float_as_int(aa.z)], wself);
    }
  }
  {
    const int cnt = cnt_s[t * NBS + B];
    const unsigned int* pst = part_s + ((size_t)t * NBS + B) * CAPS;
    int i = tid;
    for (; i + 768 < cnt; i += 1024) {   // 4 independent chains in flight
      unsigned int r0 = pst[i], r1 = pst[i + 256], r2 = pst[i + 512], r3 = pst[i + 768];
      float4 x0 = auxt[r0 & 32767], x1 = auxt[r1 & 32767];
      float4 x2 = auxt[r2 & 32767], x3 = auxt[r3 & 32767];
      int s0 = (int)(r0 >> 15) & 63, s1 = (int)(r1 >> 15) & 63;
      int s2 = (int)(r2 >> 15) & 63, s3 = (int)(r3 >> 15) & 63;
      float v0 = __shfl(a0, s0), v1 = __shfl(a0, s1);
      float v2 = __shfl(a0, s2), v3 = __shfl(a0, s3);
      float w0 = __expf(lrelu(v0 + x0.x)) * x0.y;
      float w1 = __expf(lrelu(v1 + x1.x)) * x1.y;
      float w2 = __expf(lrelu(v2 + x2.x)) * x2.y;
      float w3 = __expf(lrelu(v3 + x3.x)) * x3.y;
      atomicAdd(&clT[s0 * 64 + __float_as_int(x0.z)], w0);
      atomicAdd(&clT[s1 * 64 + __float_as_int(x1.z)], w1);
      atomicAdd(&clT[s2 * 64 + __float_as_int(x2.z)], w2);
      atomicAdd(&clT[s3 * 64 + __float_as_int(x3.z)], w3);
    }
    for (; i < cnt; i += 256) {
      unsigned int rec = pst[i];
      int s6 = (int)(rec >> 15) & 63;
      float4 aa = auxt[rec & 32767];
      float v = __shfl(a0, s6);
      float w2 = __expf(lrelu(v + aa.x)) * aa.y;
      atomicAdd(&clT[s6 * 64 + __float_as_int(aa.z)], w2);
    }
  }
  __syncthreads();
  // build clA bf16 [b][k] (stride 72 shorts = 36 uints) from clT [k][b]
  {
    unsigned int* clAu = (unsigned int*)clA;
    const int b = tid & 63, seg = tid >> 6;   // seg 0..3
    #pragma unroll
    for (int q = 0; q < 8; ++q) {
      int up = seg * 8 + q;                   // uint index 0..31 (k pair)
      int k = up * 2;
      unsigned int pk = (unsigned int)f2bf(clT[k * 64 + b]) |
                        ((unsigned int)f2bf(clT[(k + 1) * 64 + b]) << 16);
      clAu[b * 36 + up] = pk;
    }
  }
  __syncthreads();   // clT reads complete; safe to overwrite region with xT
  // build xT bf16 [d][k] (stride 72 shorts) from pair-packed xb rows
  {
    const unsigned int* xrow = xb + (size_t)t * NNODES * 64;
    unsigned int* xTu = (unsigned int*)xT;
    const int j = tid & 63, kp = tid >> 6;    // kp 0..3
    #pragma unroll
    for (int p = 0; p < 8; ++p) {
      int kk = (kp * 8 + p) * 2;
      int r0 = B * 64 + kk;     r0 = (r0 < NNODES) ? r0 : (NNODES - 1);
      int r1 = B * 64 + kk + 1; r1 = (r1 < NNODES) ? r1 : (NNODES - 1);
      unsigned int ua = xrow[(size_t)r0 * 64 + j];   // (x[kk][j], x[kk][j+64])
      unsigned int ub = xrow[(size_t)r1 * 64 + j];
      xTu[j * 36 + (kk >> 1)]        = (ua & 0xffffu) | (ub << 16);
      xTu[(j + 64) * 36 + (kk >> 1)] = (ua >> 16) | (ub & 0xffff0000u);
    }
  }
  __syncthreads();
  // MFMA: wave w owns b-stripe bs = w*16; D[b][d] over d = 0..127
  const int ln = lane & 15, hi = lane >> 4;
  const int bs = w * 16;
  f32x4 acc[8] = {};
  #pragma unroll
  for (int kh = 0; kh < 2; ++kh) {
    short8 a = *(const short8*)&clA[(bs + ln) * 72 + kh * 32 + hi * 8];
    #pragma unroll
    for (int ni = 0; ni < 8; ++ni) {
      short8 bfr = *(const short8*)&xT[(ni * 16 + ln) * 72 + kh * 32 + hi * 8];
      acc[ni] = __builtin_amdgcn_mfma_f32_16x16x32_bf16(a, bfr, acc[ni], 0, 0, 0);
    }
  }
  unsigned int* pp = ppart + ((size_t)t * NBS + B) * BGR * 64;
  #pragma unroll
  for (int ni = 0; ni < 4; ++ni)
    #pragma unroll
    for (int r = 0; r < 4; ++r) {   // pair-pack (d, d+64) = (acc[ni], acc[ni+4])
      unsigned int pk = (unsigned int)f2bf(acc[ni][r]) |
                        ((unsigned int)f2bf(acc[ni + 4][r]) << 16);
      pp[(bs + hi * 4 + r) * 64 + ni * 16 + ln] = pk;
    }
}

// ---------------- pooled = (sum_B P) @ W * invc + gat_bias  (block per (t,b))
// 128 threads: tid<64 sums buckets [0,157), tid>=64 sums [157,313); LDS combine.
__global__ __launch_bounds__(128) void k_pw(
    const unsigned int* __restrict__ ppart, const int* __restrict__ starts,
    const float* __restrict__ W, const float* __restrict__ gat_bias,
    float* __restrict__ pooled) {
  __shared__ float srow[128];
  __shared__ float psum[2][128];
  const int tb = blockIdx.x;       // 0..511
  const int t = tb >> 6, b = tb & 63;
  const int d = threadIdx.x & 63, half = threadIdx.x >> 6;
  {
    float slo = 0.f, shi = 0.f;
    const int B0 = half ? 157 : 0, B1 = half ? NBS : 157;
    const unsigned int* pp = ppart + ((size_t)t * NBS * BGR + b) * 64 + d;
    #pragma unroll 4
    for (int B = B0; B < B1; ++B) {
      unsigned int u = pp[(size_t)B * BGR * 64];
      slo += bf_lo(u); shi += bf_hi(u);
    }
    psum[half][d] = slo; psum[half][64 + d] = shi;
  }
  __syncthreads();
  if (threadIdx.x < 128) srow[threadIdx.x] = psum[0][threadIdx.x] + psum[1][threadIdx.x];
  __syncthreads();
  const float invc = 1.0f / (float)max(starts[b + 1] - starts[b], 1);
  const int dd = threadIdx.x;
  float o = 0.f;
  #pragma unroll 8
  for (int k = 0; k < 128; ++k) o += srow[k] * W[k * 128 + dd];
  pooled[(size_t)(t * BGR + b) * HDIM + dd] = o * invc + gat_bias[dd];
}

// ---------------- LSTM over T + fused FC (one block per batch row b)
__global__ __launch_bounds__(512) void k_lstm_fc(
    const float* __restrict__ pooled,
    const float* __restrict__ W_ih, const float* __restrict__ W_hh,
    const float* __restrict__ b_ih, const float* __restrict__ b_hh,
    const float* __restrict__ z, const float* __restrict__ fc_W,
    const float* __restrict__ fc_b, float* __restrict__ out) {
  const int b = blockIdx.x;
  const int g = threadIdx.x;
  __shared__ unsigned int wpk[512 * 65];
  __shared__ float hv[128], cv[128], part[512];
  __shared__ float pool8[TT][128];
  __shared__ float fcp[16][17];

  #pragma unroll 2
  for (int it = 0; it < 64; ++it) {
    int i = g + it * 512;
    int gr = i >> 6, j = i & 63;
    float2 wv = *(const float2*)(W_hh + (size_t)gr * HDIM + j * 2);
    wpk[gr * 65 + j] = (unsigned int)f2bf(wv.x) | ((unsigned int)f2bf(wv.y) << 16);
  }
  #pragma unroll
  for (int i = 0; i < 2; ++i) {
    int idx = g + i * 512;
    int t = idx >> 7, k = idx & 127;
    pool8[t][k] = pooled[((size_t)t * BGR + b) * HDIM + k];
  }
  if (g < 128) { hv[g] = 0.f; cv[g] = 0.f; }
  __syncthreads();

  float gx[8] = {};
  {
    const float4* wi = (const float4*)(W_ih + (size_t)g * HDIM);
    #pragma unroll 2
    for (int k4 = 0; k4 < 32; ++k4) {
      float4 wv = wi[k4];
      #pragma unroll
      for (int t = 0; t < TT; ++t) {
        float4 p = *(const float4*)(&pool8[t][k4 * 4]);
        gx[t] += wv.x * p.x + wv.y * p.y + wv.z * p.z + wv.w * p.w;
      }
    }
  }
  const float bsum = b_ih[g] + b_hh[g];
  const unsigned int* wr = &wpk[g * 65];
  const float4* hv4 = (const float4*)hv;
  #pragma unroll
  for (int t = 0; t < TT; ++t) {
    float s = gx[t] + bsum;
    #pragma unroll 8
    for (int j2 = 0; j2 < 32; ++j2) {
      unsigned int w0 = wr[2 * j2], w1 = wr[2 * j2 + 1];
      float4 hh = hv4[j2];
      s += bf_lo(w0) * hh.x + bf_hi(w0) * hh.y + bf_lo(w1) * hh.z + bf_hi(w1) * hh.w;
    }
    part[g] = s;
    __syncthreads();
    if (g < 128) {
      float ig = sigmoidf(part[g]);
      float fg = sigmoidf(part[128 + g]);
      float gc = tanh_fast(part[256 + g]);
      float og = sigmoidf(part[384 + g]);
      float c = fg * cv[g] + ig * gc;
      cv[g] = c;
      hv[g] = og * tanh_fast(c);
    }
    __syncthreads();
  }
  if (g < 256) {
    const int c = g >> 4, kp = g & 15;
    float s = 0.f;
    for (int k = kp * 16; k < kp * 16 + 16; ++k) {
      float v = (k < 128) ? hv[k] : z[(size_t)b * HDIM + (k - 128)];
      s += v * fc_W[(size_t)c * 256 + k];
    }
    fcp[c][kp] = s;
  }
  __syncthreads();
  if (g < 16) {
    float r = fc_b[g];
    #pragma unroll
    for (int k = 0; k < 16; ++k) r += fcp[g][k];
    out[(size_t)b * NCLS + g] = r;
  }
}

extern "C" void kernel_launch(void* const* d_in, const int* in_sizes, int n_in,
                              void* d_out, int out_size, void* d_ws, size_t ws_size,
                              hipStream_t stream) {
  const float* x       = (const float*)d_in[0];
  const int*   ei      = (const int*)d_in[1];
  const int*   batch   = (const int*)d_in[2];
  const float* z       = (const float*)d_in[3];
  const float* gat_W   = (const float*)d_in[4];
  const float* att_src = (const float*)d_in[5];
  const float* att_dst = (const float*)d_in[6];
  const float* gat_bias= (const float*)d_in[7];
  const float* W_ih    = (const float*)d_in[8];
  const float* W_hh    = (const float*)d_in[9];
  const float* b_ih    = (const float*)d_in[10];
  const float* b_hh    = (const float*)d_in[11];
  const float* fc_W    = (const float*)d_in[12];
  const float* fc_b    = (const float*)d_in[13];
  float* out = (float*)d_out;

  char* ws = (char*)d_ws;
  size_t off = 0;
  auto alloc = [&](size_t bytes) {
    void* p = (void*)(ws + off);
    off += (bytes + 255) & ~(size_t)255;
    return p;
  };
  float*  as_    = (float*)alloc((size_t)TT * NNODES * 4);
  float*  ad_    = (float*)alloc((size_t)TT * NNODES * 4);
  float*  denom  = (float*)alloc((size_t)TT * NNODES * 4);
  float4* aux4   = (float4*)alloc((size_t)TT * NNODES * 16);                      // 2.56 MB
  int*    cnt2   = (int*)alloc((size_t)TT * (NBD + NBS) * 4);       // cnt_d | cnt_s (one memset)
  int*    cnt_d  = cnt2;
  int*    cnt_s  = cnt2 + TT * NBD;
  unsigned int* part_d = (unsigned int*)alloc(((size_t)TT * NBD + 1) * CAPD * 4); // 14.2 MB (+slack)
  unsigned int* part_s = (unsigned int*)alloc(((size_t)TT * NBS + 1) * CAPS * 4); // 15.4 MB (+slack)
  unsigned int* ppart  = (unsigned int*)alloc((size_t)TT * NBS * BGR * 64 * 4);   // 41.0 MB bf16-packed
  unsigned int* xb     = (unsigned int*)alloc((size_t)TT * NNODES * 64 * 4);      // 40.96 MB bf16-packed
  float* uvec  = (float*)alloc(128 * 4);
  float* vvec  = (float*)alloc(128 * 4);
  float* pooled = (float*)alloc((size_t)TT * BGR * HDIM * 4);
  int* starts = (int*)alloc((BGR + 1) * 4);
  (void)ws_size; (void)in_sizes; (void)n_in; (void)out_size;

  hipMemsetAsync(cnt2, 0, (size_t)TT * (NBD + NBS) * 4, stream);

  k_prep<<<1, 256, 0, stream>>>(gat_W, att_src, att_dst, uvec, vvec);
  k_gemv<<<(TT * NNODES) / 64, 256, 0, stream>>>(x, uvec, vvec, as_, ad_, denom, xb);
  k_scat<<<dim3(CB, TT), 256, 0, stream>>>(ei, cnt_d, cnt_s, part_d, part_s);
  k_denomB<<<dim3(NBD, TT), 256, 0, stream>>>(part_d, cnt_d, as_, ad_, denom, batch, aux4, starts);
  k_cpgemm<<<dim3(NBS, TT), 256, 0, stream>>>(part_s, cnt_s, as_, aux4, xb, ppart);
  k_pw<<<TT * BGR, 128, 0, stream>>>(ppart, starts, gat_W, gat_bias, pooled);
  k_lstm_fc<<<BGR, 512, 0, stream>>>(pooled, W_ih, W_hh, b_ih, b_hh, z, fc_W, fc_b, out);
}